// Round 9
// baseline (254.443 us; speedup 1.0000x reference)
//
#include <hip/hip_runtime.h>

#define HNEG (-1000000000.0f)
// Sentinel in the base-2 log domain: HNEG * (1/ln2). The combine pass
// multiplies by ln2, returning this to exactly the reference's NEG scale.
#define HNEG2 (-1.44269504e9f)
#define INVLN2 1.44269504088896341f
#define LN2F 0.69314718055994531f

constexpr int Nc = 128;
constexpr int Mc = 128;
constexpr int CELLS = Nc * Mc * 3;

// Raw HW transcendentals: v_exp_f32 computes 2^x, v_log_f32 computes log2(x).
__device__ __forceinline__ float ex2(float x) {
  return __builtin_amdgcn_exp2f(x);
}
__device__ __forceinline__ float lg2(float x) {
  return __builtin_amdgcn_logf(x);
}

// --- Padded diag-major layout (for thd LOADS; float2-aligned) --------------
__device__ __host__ constexpr int dpoff(int d) {
  return d <= 128 ? (d * (d + 1)) / 2 + ((d + 1) >> 1)
                  : 16448 - ((255 - d) * (256 - d)) / 2 + ((d - 127) >> 1);
}
__device__ __forceinline__ int dlod(int d) { return d > 127 ? d - 127 : 0; }
__device__ __forceinline__ int sidx(int d, int j) {
  const int lo = dlod(d);
  return dpoff(d) + j - lo + (lo & 1);
}
__device__ __forceinline__ int sidx_u(int d) {
  const int lo = dlod(d);
  return dpoff(d) - lo + (lo & 1);
}
constexpr int PCELLS = 16512;
constexpr int PFLOATS = PCELLS * 3;

// --- Compact diag-major layout (for alpha/g STORES; coalesced runs) --------
__device__ __host__ constexpr int codd(int d) {
  return d <= 128 ? ((d * (d + 1)) >> 1)
                  : 8256 + (d - 128) * 127 - (((d - 128) * (d - 129)) >> 1);
}
constexpr int AWSTRIDE = CELLS + 16;  // row-mode alpha block + dump pad
constexpr int CDSTRIDE = CELLS + 8;   // diag-mode block + dump pad

__device__ __forceinline__ float lse3(float a, float b, float c) {
  float mx = fmaxf(fmaxf(a, b), c);
  return mx + __logf(__expf(a - mx) + __expf(b - mx) + __expf(c - mx));
}

// lane l gets src[l-1]; lane 0 gets `fill`. Pure-VALU DPP wave_shr:1.
__device__ __forceinline__ float shr1f(float src, float fill) {
  return __int_as_float(__builtin_amdgcn_update_dpp(
      __float_as_int(fill), __float_as_int(src), 0x138, 0xF, 0xF, false));
}

// ---------------------------------------------------------------------------
// K1: theta row-major -> theta_diag (padded diag-major), pre-scaled by 1/ln2.
// ---------------------------------------------------------------------------
__global__ __launch_bounds__(256) void transpose_kernel(
    const float* __restrict__ theta, float* __restrict__ thd) {
  const int b = blockIdx.x;
  const int tile = blockIdx.y;  // 0..3
  const int i0 = (tile >> 1) * 64, j0 = (tile & 1) * 64;
  const int t = threadIdx.x;
  __shared__ float lds[64 * 192];
  float4* lds4 = (float4*)lds;
  const float4* src4 = (const float4*)(theta + (size_t)b * CELLS);
  float* dst = thd + (size_t)b * PFLOATS;
  const int cbase = (j0 >> 6) * 48;
  for (int f = t; f < 64 * 48; f += 256) {
    const int r = f / 48, c4 = f - r * 48;
    lds4[f] = src4[(size_t)(i0 + r) * 96 + cbase + c4];
  }
  __syncthreads();
  const int g = t >> 6, w = t & 63;
  for (int ld = g; ld < 127; ld += 4) {
    const int d = i0 + j0 + ld;
    const int ljlo = ld > 63 ? ld - 63 : 0;
    const int ljhi = ld < 63 ? ld : 63;
    const int L = (ljhi - ljlo + 1) * 3;
    const int base = sidx(d, j0 + ljlo) * 3;
    for (int e = w; e < L; e += 64) {
      const int lj = ljlo + e / 3, s = e - (e / 3) * 3;
      dst[base + e] = lds[(ld - lj) * 192 + lj * 3 + s] * INVLN2;
    }
  }
}

#define DECL3(p) float p##0, p##1, p##2

// ---------------------------------------------------------------------------
// K2: fb4 — 4 waves per batch, 1 column per lane, base-2 log domain.
//   wave 0: fwd cols 0-63   (AHEAD)   wave 1: fwd cols 64-127 (BEHIND)
//   wave 2: bwd fcols 0-63  (AHEAD)   wave 3: bwd fcols 64-127 (BEHIND)
// template<DIAG>: true  -> alpha/g stored COMPACT-DIAG (coalesced 768B runs;
//                          removes the scattered-store line bottleneck),
//                 false -> row-major stores (round-8 proven path).
// ---------------------------------------------------------------------------

#define FLOAD(TH, dd) do {                                                     \
    const int dc_ = (dd) > 254 ? 254 : (dd);                                   \
    const int su_ = __builtin_amdgcn_readfirstlane(sidx_u(dc_));               \
    const float* p_ = thd + su_ * 3 + 3 * j;                                   \
    TH##0 = p_[0]; TH##1 = p_[1]; TH##2 = p_[2];                               \
  } while (0)

#define FSTEP(TH, dd) do {                                                     \
    float4 hv_;                                                                \
    if (isB && l == 0) hv_ = *(const float4*)&ringF[(dd) & 31][0];             \
    const int i_ = (dd) - j;                                                   \
    const bool ok_ = (unsigned)i_ < (unsigned)Nc;                              \
    const float g0 = S2m + lg2(S2w0 * E00 + S2w1 * E10 + S2w2 * E20);          \
    const float g1 = Pm + lg2(Pw0 * E01 + Pw1 * E11 + Pw2 * E21);              \
    const float g2 = S1m + lg2(S1w0 * E02 + S1w1 * E12 + S1w2 * E22);          \
    const float c0 = ok_ ? TH##0 + g0 : HNEG2;                                 \
    const float c1 = ok_ ? TH##1 + g1 : HNEG2;                                 \
    const float c2 = ok_ ? TH##2 + g2 : HNEG2;                                 \
    float* o_;                                                                 \
    if constexpr (DIAG) {                                                      \
      const int so_ = __builtin_amdgcn_readfirstlane(                          \
          (codd(dd) - dlod(dd)) * 3);                                          \
      o_ = ok_ ? p1 + so_ + 3 * j : dmpF;                                      \
    } else {                                                                   \
      o_ = ok_ ? p1 + (i_ * Mc + j) * 3 : dmpF;                                \
    }                                                                          \
    o_[0] = c0; o_[1] = c1; o_[2] = c2;                                        \
    const float m_ = fmaxf(fmaxf(c0, c1), c2);                                 \
    const float w0_ = ex2(c0 - m_), w1_ = ex2(c1 - m_), w2_ = ex2(c2 - m_);    \
    if (!isB && l == 63)                                                       \
      *(float4*)&ringF[(dd) & 31][0] = make_float4(m_, w0_, w1_, w2_);         \
    S2m = S1m; S2w0 = S1w0; S2w1 = S1w1; S2w2 = S1w2;                          \
    float nm_ = shr1f(m_, HNEG2);                                              \
    float n0_ = shr1f(w0_, 1.f), n1_ = shr1f(w1_, 1.f), n2_ = shr1f(w2_, 1.f); \
    if (isB && l == 0) { nm_ = hv_.x; n0_ = hv_.y; n1_ = hv_.z; n2_ = hv_.w; } \
    S1m = nm_; S1w0 = n0_; S1w1 = n1_; S1w2 = n2_;                             \
    Pm = m_; Pw0 = w0_; Pw1 = w1_; Pw2 = w2_;                                  \
  } while (0)

#define BLOAD(TH, dd) do {                                                     \
    int dor_ = 254 - (dd); if (dor_ < 0) dor_ = 0;                             \
    const int su_ = __builtin_amdgcn_readfirstlane(sidx_u(dor_));              \
    const float* p_ = thd + su_ * 3 + 3 * jj;                                  \
    TH##0 = p_[0]; TH##1 = p_[1]; TH##2 = p_[2];                               \
  } while (0)

#define BSTEP(TH, dd) do {                                                     \
    float2 hv_;                                                                \
    if (isB && l == 0) hv_ = *(const float2*)&ringB[(dd) & 31][0];             \
    const int i_ = Nc - 1 - (dd) + q;                                          \
    const bool ok_ = (unsigned)i_ < (unsigned)Nc;                              \
    const float v0 = S2u0, v1 = pu1, v2 = S1u2;                                \
    const float mv = fmaxf(fmaxf(v0, v1), v2);                                 \
    const float w0_ = ex2(v0 - mv), w1_ = ex2(v1 - mv), w2_ = ex2(v2 - mv);    \
    float g0 = mv + lg2(w0_ * E00 + w1_ * E01 + w2_ * E02);                    \
    float g1 = mv + lg2(w0_ * E10 + w1_ * E11 + w2_ * E12);                    \
    float g2 = mv + lg2(w0_ * E20 + w1_ * E21 + w2_ * E22);                    \
    if ((dd) == 0 && !isB && l == 0) { g0 = 0.f; g1 = 0.f; g2 = 0.f; }         \
    const float u0 = ok_ ? g0 + TH##0 : HNEG2;                                 \
    const float u1 = ok_ ? g1 + TH##1 : HNEG2;                                 \
    const float u2 = ok_ ? g2 + TH##2 : HNEG2;                                 \
    float* o_;                                                                 \
    if constexpr (DIAG) {                                                      \
      const int dor_ = 254 - (dd);                                             \
      const int so_ = __builtin_amdgcn_readfirstlane(                          \
          (codd(dor_) - dlod(dor_)) * 3);                                      \
      o_ = ok_ ? p2 + so_ + 3 * jj : dmpB2;                                    \
    } else {                                                                   \
      o_ = ok_ ? p2 + (i_ * Mc + jj) * 3 : dmpB2;                              \
    }                                                                          \
    o_[0] = g0; o_[1] = g1; o_[2] = g2;                                        \
    if (!isB && l == 63)                                                       \
      *(float2*)&ringB[(dd) & 31][0] = make_float2(u0, u2);                    \
    pu1 = u1;                                                                  \
    S2u0 = S1u0;                                                               \
    float n0_ = shr1f(u0, HNEG2), n2_ = shr1f(u2, HNEG2);                      \
    if (isB && l == 0) { n0_ = hv_.x; n2_ = hv_.y; }                           \
    S1u0 = n0_; S1u2 = n2_;                                                    \
  } while (0)

#define FBLK8(D) do {                                                          \
    FSTEP(x0, (D) + 0); FLOAD(x0, (D) + 8);                                    \
    FSTEP(x1, (D) + 1); FLOAD(x1, (D) + 9);                                    \
    FSTEP(x2, (D) + 2); FLOAD(x2, (D) + 10);                                   \
    FSTEP(x3, (D) + 3); FLOAD(x3, (D) + 11);                                   \
    FSTEP(x4, (D) + 4); FLOAD(x4, (D) + 12);                                   \
    FSTEP(x5, (D) + 5); FLOAD(x5, (D) + 13);                                   \
    FSTEP(x6, (D) + 6); FLOAD(x6, (D) + 14);                                   \
    FSTEP(x7, (D) + 7); FLOAD(x7, (D) + 15);                                   \
  } while (0)

#define FBLK7(D) do {                                                          \
    FSTEP(x0, (D) + 0); FSTEP(x1, (D) + 1); FSTEP(x2, (D) + 2);                \
    FSTEP(x3, (D) + 3); FSTEP(x4, (D) + 4); FSTEP(x5, (D) + 5);                \
    FSTEP(x6, (D) + 6);                                                        \
  } while (0)

#define BBLK8(D) do {                                                          \
    BSTEP(x0, (D) + 0); BLOAD(x0, (D) + 8);                                    \
    BSTEP(x1, (D) + 1); BLOAD(x1, (D) + 9);                                    \
    BSTEP(x2, (D) + 2); BLOAD(x2, (D) + 10);                                   \
    BSTEP(x3, (D) + 3); BLOAD(x3, (D) + 11);                                   \
    BSTEP(x4, (D) + 4); BLOAD(x4, (D) + 12);                                   \
    BSTEP(x5, (D) + 5); BLOAD(x5, (D) + 13);                                   \
    BSTEP(x6, (D) + 6); BLOAD(x6, (D) + 14);                                   \
    BSTEP(x7, (D) + 7); BLOAD(x7, (D) + 15);                                   \
  } while (0)

#define BBLK7(D) do {                                                          \
    BSTEP(x0, (D) + 0); BSTEP(x1, (D) + 1); BSTEP(x2, (D) + 2);                \
    BSTEP(x3, (D) + 3); BSTEP(x4, (D) + 4); BSTEP(x5, (D) + 5);                \
    BSTEP(x6, (D) + 6);                                                        \
  } while (0)

#define BLOCK_BARRIER() do {                                                   \
    __builtin_amdgcn_sched_barrier(0);                                         \
    asm volatile("s_waitcnt lgkmcnt(0)" ::: "memory");                         \
    __builtin_amdgcn_s_barrier();                                              \
    __builtin_amdgcn_sched_barrier(0);                                         \
  } while (0)

template <bool DIAG>
__global__ __launch_bounds__(256, 1) void fb4_kernel(
    const float* __restrict__ thd_, const float* __restrict__ A,
    float* __restrict__ p1_, float* __restrict__ logZ_ws,
    float* __restrict__ p2_) {
  const int b = blockIdx.x;
  const int wid = threadIdx.x >> 6;
  const int l = threadIdx.x & 63;
  const float* thd = thd_ + (size_t)b * PFLOATS;
  const float* Ab = A + b * 9;
  const float E00 = __expf(Ab[0]), E01 = __expf(Ab[1]), E02 = __expf(Ab[2]);
  const float E10 = __expf(Ab[3]), E11 = __expf(Ab[4]), E12 = __expf(Ab[5]);
  const float E20 = __expf(Ab[6]), E21 = __expf(Ab[7]), E22 = __expf(Ab[8]);

  __shared__ float ringF[32][4];  // col63 fwd state (m,w0,w1,w2) per step&31
  __shared__ float ringB[32][2];  // col63 bwd state (u0,u2) per step&31

  constexpr int P1S = DIAG ? CDSTRIDE : AWSTRIDE;
  constexpr int P2S = DIAG ? CDSTRIDE : CELLS;
  float* p1 = p1_ + (size_t)b * P1S;
  float* p2 = p2_ + (size_t)b * P2S;
  float* dmpF = p1 + CELLS;                        // pad in p1 block
  float* dmpB2 = DIAG ? p2 + CELLS : p1 + CELLS;   // row-mode: p2=out, no pad

  if (wid < 2) {
    // ----------------- forward (base-2), 1 col/lane -----------------
    const bool isB = (wid == 1);
    const int j = (isB ? 64 : 0) + l;

    float Pm = HNEG2, Pw0 = 1.f, Pw1 = 1.f, Pw2 = 1.f;
    float S1m = HNEG2, S1w0 = 1.f, S1w1 = 1.f, S1w2 = 1.f;
    float S2m = HNEG2, S2w0 = 1.f, S2w1 = 1.f, S2w2 = 1.f;
    // Origin (0,0): lane 0 of wave 0, step 0: g0 = 0 via S2 init.
    if (!isB && l == 0) { S2m = 0.f; S2w0 = 1.0f / E00; S2w1 = 0.f; S2w2 = 0.f; }

    DECL3(x0); DECL3(x1); DECL3(x2); DECL3(x3);
    DECL3(x4); DECL3(x5); DECL3(x6); DECL3(x7);
    FLOAD(x0, 0); FLOAD(x1, 1); FLOAD(x2, 2); FLOAD(x3, 3);
    FLOAD(x4, 4); FLOAD(x5, 5); FLOAD(x6, 6); FLOAD(x7, 7);

    for (int t = 0; t <= 32; ++t) {
      const bool act = isB ? (t >= 1) : (t < 32);
      const int D = (isB ? (t - 1) : t) * 8;
      if (act) {
        if (D == 248) FBLK7(D); else FBLK8(D);
      }
      BLOCK_BARRIER();
    }
    // lane 63 of wave 1 holds cell (127,127) after step 254.
    if (isB && l == 63) logZ_ws[b] = Pm + lg2(Pw0 + Pw1 + Pw2);
  } else {
    // ----------------- backward (beta only, base-2), 1 col/lane -----
    const bool isB = (wid == 3);
    const int q = (isB ? 64 : 0) + l;  // flipped col
    const int jj = Mc - 1 - q;         // orig col

    float pu1 = HNEG2;
    float S1u0 = HNEG2, S1u2 = HNEG2, S2u0 = HNEG2;

    DECL3(x0); DECL3(x1); DECL3(x2); DECL3(x3);
    DECL3(x4); DECL3(x5); DECL3(x6); DECL3(x7);
    BLOAD(x0, 0); BLOAD(x1, 1); BLOAD(x2, 2); BLOAD(x3, 3);
    BLOAD(x4, 4); BLOAD(x5, 5); BLOAD(x6, 6); BLOAD(x7, 7);

    for (int t = 0; t <= 32; ++t) {
      const bool act = isB ? (t >= 1) : (t < 32);
      const int D = (isB ? (t - 1) : t) * 8;
      if (act) {
        if (D == 248) BBLK7(D); else BBLK8(D);
      }
      BLOCK_BARRIER();
    }
  }
}

// ---------------------------------------------------------------------------
// K3a (DIAG path): dual-source diag->row combine.
// Reads alpha-diag + g-diag (coalesced runs), sums into an LDS tile,
// writes out = (a+g-logZ)*ln2 row-major with float4 stores.
// ---------------------------------------------------------------------------
__global__ __launch_bounds__(256) void combine_diag_kernel(
    const float* __restrict__ ad_, const float* __restrict__ gd_,
    const float* __restrict__ logZ_ws, float4* __restrict__ out4) {
  const int b = blockIdx.x;
  const int tile = blockIdx.y;  // 0..3
  const int i0 = (tile >> 1) * 64, j0 = (tile & 1) * 64;
  const int t = threadIdx.x;
  __shared__ float lds[64 * 192];
  const float* ad = ad_ + (size_t)b * CDSTRIDE;
  const float* gd = gd_ + (size_t)b * CDSTRIDE;
  const float lz = logZ_ws[b];
  const int g = t >> 6, w = t & 63;
  for (int ld = g; ld < 127; ld += 4) {
    const int d = i0 + j0 + ld;
    const int ljlo = ld > 63 ? ld - 63 : 0;
    const int ljhi = ld < 63 ? ld : 63;
    const int L = (ljhi - ljlo + 1) * 3;
    const int base = (codd(d) + (j0 + ljlo) - dlod(d)) * 3;
    for (int e = w; e < L; e += 64) {
      const int lj = ljlo + e / 3, s = e - (e / 3) * 3;
      lds[(ld - lj) * 192 + lj * 3 + s] = ad[base + e] + gd[base + e];
    }
  }
  __syncthreads();
  const size_t ob4 = (size_t)b * 12288 + (j0 >> 6) * 48;
  const float4* lds4 = (const float4*)lds;
  for (int f = t; f < 64 * 48; f += 256) {
    const int r = f / 48, c4 = f - r * 48;
    const float4 v = lds4[r * 48 + c4];
    out4[ob4 + (size_t)(i0 + r) * 96 + c4] =
        make_float4((v.x - lz) * LN2F, (v.y - lz) * LN2F, (v.z - lz) * LN2F,
                    (v.w - lz) * LN2F);
  }
}

// ---------------------------------------------------------------------------
// K3b (ROW path, round-8): streaming combine. out holds g row-major, p1
// holds alpha row-major. out = (a+g-logZ)*ln2.
// ---------------------------------------------------------------------------
__global__ __launch_bounds__(256) void combine_kernel(
    const float4* __restrict__ aw4, const float* __restrict__ logZ_ws,
    float4* __restrict__ out4) {
  const int b = blockIdx.x;
  const float lz = logZ_ws[b];
  const int off = blockIdx.y * 1024 + threadIdx.x;
  const size_t ab = (size_t)b * (AWSTRIDE / 4);
  const size_t obx = (size_t)b * 12288;
#pragma unroll
  for (int k = 0; k < 4; ++k) {
    const size_t i = off + (size_t)k * 256;
    const float4 a = aw4[ab + i];
    const float4 g = out4[obx + i];
    out4[obx + i] =
        make_float4((a.x + g.x - lz) * LN2F, (a.y + g.y - lz) * LN2F,
                    (a.z + g.z - lz) * LN2F, (a.w + g.w - lz) * LN2F);
  }
}

// ---------------------------------------------------------------------------
// Fallback (known-correct ~355 us): used only if ws small.
// ---------------------------------------------------------------------------
__global__ __launch_bounds__(128) void fwd_fb(const float* __restrict__ theta,
                                              const float* __restrict__ A,
                                              float* __restrict__ out) {
  const int b = blockIdx.x;
  const int j = threadIdx.x;
  const float* th = theta + (size_t)b * CELLS;
  float* ob = out + (size_t)b * CELLS;

  __shared__ float sA[9];
  __shared__ float ring[3][Mc + 1][3];
  if (j < 9) sA[j] = A[b * 9 + j];
  {
    float* rf = &ring[0][0][0];
    for (int t = j; t < 3 * (Mc + 1) * 3; t += Mc) rf[t] = HNEG;
  }
  __syncthreads();
  const float A00 = sA[0], A01 = sA[1], A02 = sA[2];
  const float A10 = sA[3], A11 = sA[4], A12 = sA[5];
  const float A20 = sA[6], A21 = sA[7], A22 = sA[8];

  float p0 = HNEG, p1 = HNEG, p2 = HNEG;
  float tc0 = 0.f, tc1 = 0.f, tc2 = 0.f, tn0 = 0.f, tn1 = 0.f, tn2 = 0.f;
  if (j == 0) { tc0 = th[0]; tc1 = th[1]; tc2 = th[2]; }
  if (j <= 1) {
    const int i1 = 1 - j;
    const float* p = th + (i1 * Mc + j) * 3;
    tn0 = p[0]; tn1 = p[1]; tn2 = p[2];
  }
  int s0 = 0, s1 = 2, s2 = 1;
  for (int d = 0; d < Nc + Mc - 1; ++d) {
    const int i = d - j;
    float tf0 = 0.f, tf1 = 0.f, tf2 = 0.f;
    const int ip = i + 2;
    if (ip >= 0 && ip < Nc) {
      const float* p = th + (ip * Mc + j) * 3;
      tf0 = p[0]; tf1 = p[1]; tf2 = p[2];
    }
    float c0 = HNEG, c1 = HNEG, c2 = HNEG;
    if (i >= 0 && i < Nc) {
      const float* nd1 = ring[s1][j];
      const float* nd2 = ring[s2][j];
      float lm = lse3(nd2[0] + A00, nd2[1] + A10, nd2[2] + A20);
      if (i == 0 && j == 0) lm = 0.0f;
      float lx = lse3(p0 + A01, p1 + A11, p2 + A21);
      float ly = lse3(nd1[0] + A02, nd1[1] + A12, nd1[2] + A22);
      c0 = tc0 + lm; c1 = tc1 + lx; c2 = tc2 + ly;
      float* o = ob + (i * Mc + j) * 3;
      o[0] = c0; o[1] = c1; o[2] = c2;
    }
    float* w = ring[s0][j + 1];
    w[0] = c0; w[1] = c1; w[2] = c2;
    __syncthreads();
    p0 = c0; p1 = c1; p2 = c2;
    tc0 = tn0; tc1 = tn1; tc2 = tn2;
    tn0 = tf0; tn1 = tf1; tn2 = tf2;
    const int t = s2; s2 = s1; s1 = s0; s0 = t;
  }
}

__global__ __launch_bounds__(128) void bwd_fb(const float* __restrict__ theta,
                                              const float* __restrict__ A,
                                              float* __restrict__ ob_) {
  const int b = blockIdx.x;
  const int q = threadIdx.x;
  const float* th = theta + (size_t)b * CELLS;
  float* ob = ob_ + (size_t)b * CELLS;

  __shared__ float sA[9];
  __shared__ float ring[3][Mc + 1][3];
  __shared__ float sZ;
  if (q < 9) sA[q] = A[b * 9 + q];
  {
    float* rf = &ring[0][0][0];
    for (int t = q; t < 3 * (Mc + 1) * 3; t += Mc) rf[t] = HNEG;
  }
  if (q == 0) {
    sZ = lse3(ob[(Nc * Mc - 1) * 3 + 0], ob[(Nc * Mc - 1) * 3 + 1],
              ob[(Nc * Mc - 1) * 3 + 2]);
  }
  __syncthreads();
  const float A00 = sA[0], A01 = sA[1], A02 = sA[2];
  const float A10 = sA[3], A11 = sA[4], A12 = sA[5];
  const float A20 = sA[6], A21 = sA[7], A22 = sA[8];
  const float logZ = sZ;

  const int jj = Mc - 1 - q;
  float pu1 = HNEG;
  float tc0 = 0.f, tc1 = 0.f, tc2 = 0.f, tn0 = 0.f, tn1 = 0.f, tn2 = 0.f;
  float ac0 = 0.f, ac1 = 0.f, ac2 = 0.f, an0 = 0.f, an1 = 0.f, an2 = 0.f;
  if (q == 0) {
    const float* p = th + ((Nc - 1) * Mc + jj) * 3;
    tc0 = p[0]; tc1 = p[1]; tc2 = p[2];
    const float* a = ob + ((Nc - 1) * Mc + jj) * 3;
    ac0 = a[0]; ac1 = a[1]; ac2 = a[2];
  }
  if (q <= 1) {
    const int i1 = Nc - 2 + q;
    const float* p = th + (i1 * Mc + jj) * 3;
    tn0 = p[0]; tn1 = p[1]; tn2 = p[2];
    const float* a = ob + (i1 * Mc + jj) * 3;
    an0 = a[0]; an1 = a[1]; an2 = a[2];
  }
  int s0 = 0, s1 = 2, s2 = 1;
  for (int d = 0; d < Nc + Mc - 1; ++d) {
    const int p = d - q;
    const int i = Nc - 1 - p;
    float tf0 = 0.f, tf1 = 0.f, tf2 = 0.f, af0 = 0.f, af1 = 0.f, af2 = 0.f;
    const int ipf = i - 2;
    if (ipf >= 0 && ipf < Nc) {
      const float* pp = th + (ipf * Mc + jj) * 3;
      tf0 = pp[0]; tf1 = pp[1]; tf2 = pp[2];
      const float* aa = ob + (ipf * Mc + jj) * 3;
      af0 = aa[0]; af1 = aa[1]; af2 = aa[2];
    }
    float u0 = HNEG, u1 = HNEG, u2 = HNEG;
    if (p >= 0 && p < Nc) {
      const float* nd1 = ring[s1][q];
      const float* nd2 = ring[s2][q];
      const float v0 = nd2[0];
      const float v1 = pu1;
      const float v2 = nd1[2];
      float g0 = lse3(A00 + v0, A01 + v1, A02 + v2);
      float g1 = lse3(A10 + v0, A11 + v1, A12 + v2);
      float g2 = lse3(A20 + v0, A21 + v1, A22 + v2);
      if (p == 0 && q == 0) { g0 = 0.0f; g1 = 0.0f; g2 = 0.0f; }
      u0 = g0 + tc0; u1 = g1 + tc1; u2 = g2 + tc2;
      float* o = ob + (i * Mc + jj) * 3;
      o[0] = ac0 + g0 - logZ;
      o[1] = ac1 + g1 - logZ;
      o[2] = ac2 + g2 - logZ;
    }
    float* w = ring[s0][q + 1];
    w[0] = u0; w[1] = u1; w[2] = u2;
    __syncthreads();
    pu1 = u1;
    tc0 = tn0; tc1 = tn1; tc2 = tn2;
    tn0 = tf0; tn1 = tf1; tn2 = tf2;
    ac0 = an0; ac1 = an1; ac2 = an2;
    an0 = af0; an1 = af1; an2 = af2;
    const int t = s2; s2 = s1; s1 = s0; s0 = t;
  }
}

extern "C" void kernel_launch(void* const* d_in, const int* in_sizes, int n_in,
                              void* d_out, int out_size, void* d_ws, size_t ws_size,
                              hipStream_t stream) {
  const float* theta = (const float*)d_in[0];
  const float* A = (const float*)d_in[1];
  float* out = (float*)d_out;
  const int B = in_sizes[1] / 9;  // A is (B, 3, 3)

  // Tier 1: thd + alpha-diag + g-diag + logZ (coalesced-store path)
  const size_t need3 = (size_t)B * (PFLOATS + 2 * CDSTRIDE + 1) * 4;
  // Tier 2: thd + alpha-row (+pad) + logZ (round-8 path; g goes into out)
  const size_t need2 = (size_t)B * (PFLOATS + AWSTRIDE + 1) * 4;

  if (ws_size >= need3) {
    float* thd = (float*)d_ws;
    float* ad = thd + (size_t)B * PFLOATS;
    float* gd = ad + (size_t)B * CDSTRIDE;
    float* logZ_ws = gd + (size_t)B * CDSTRIDE;
    transpose_kernel<<<dim3(B, 4), dim3(256), 0, stream>>>(theta, thd);
    fb4_kernel<true><<<dim3(B), dim3(256), 0, stream>>>(thd, A, ad, logZ_ws, gd);
    combine_diag_kernel<<<dim3(B, 4), dim3(256), 0, stream>>>(
        ad, gd, logZ_ws, (float4*)out);
  } else if (ws_size >= need2) {
    float* thd = (float*)d_ws;
    float* aw = thd + (size_t)B * PFLOATS;
    float* logZ_ws = aw + (size_t)B * AWSTRIDE;
    transpose_kernel<<<dim3(B, 4), dim3(256), 0, stream>>>(theta, thd);
    fb4_kernel<false><<<dim3(B), dim3(256), 0, stream>>>(thd, A, aw, logZ_ws, out);
    combine_kernel<<<dim3(B, 12), dim3(256), 0, stream>>>(
        (const float4*)aw, logZ_ws, (float4*)out);
  } else {
    fwd_fb<<<dim3(B), dim3(128), 0, stream>>>(theta, A, out);
    bwd_fb<<<dim3(B), dim3(128), 0, stream>>>(theta, A, out);
  }
}

// Round 10
// 203.371 us; speedup vs baseline: 1.2511x; 1.2511x over previous
//
#include <hip/hip_runtime.h>

#define HNEG (-1000000000.0f)
// Sentinel in the base-2 log domain: HNEG * (1/ln2). The final combine
// multiplies by ln2, returning this to exactly the reference's NEG scale.
#define HNEG2 (-1.44269504e9f)
#define INVLN2 1.44269504088896341f
#define LN2F 0.69314718055994531f

constexpr int Nc = 128;
constexpr int Mc = 128;
constexpr int CELLS = Nc * Mc * 3;
constexpr int AWSTRIDE = CELLS + 16;  // alpha block + dump pad per batch

// Raw HW transcendentals: v_exp_f32 computes 2^x, v_log_f32 computes log2(x).
__device__ __forceinline__ float ex2(float x) {
  return __builtin_amdgcn_exp2f(x);
}
__device__ __forceinline__ float lg2(float x) {
  return __builtin_amdgcn_logf(x);
}

__device__ __forceinline__ float lse3(float a, float b, float c) {
  float mx = fmaxf(fmaxf(a, b), c);
  return mx + __logf(__expf(a - mx) + __expf(b - mx) + __expf(c - mx));
}

// lane l gets src[l-1]; lane 0 gets `fill`. Pure-VALU DPP wave_shr:1.
__device__ __forceinline__ float shr1f(float src, float fill) {
  return __int_as_float(__builtin_amdgcn_update_dpp(
      __float_as_int(fill), __float_as_int(src), 0x138, 0xF, 0xF, false));
}

__device__ __forceinline__ int clamp127(int i) {
  return i < 0 ? 0 : (i > 127 ? 127 : i);
}

// Store 3 floats at cell with EVEN column: float2 + float.
__device__ __forceinline__ void st3_even(float* o, float a, float b, float c) {
  *(float2*)o = make_float2(a, b);
  o[2] = c;
}
// Store 3 floats at cell with ODD column: float + float2.
__device__ __forceinline__ void st3_odd(float* o, float a, float b, float c) {
  o[0] = a;
  *(float2*)(o + 1) = make_float2(b, c);
}

// 6 named scalars per pipeline slot (2 cols x 3 states)
#define DECL6(p) float p##0, p##1, p##2, p##3, p##4, p##5

// ---------------------------------------------------------------------------
// FUSED kernel: fwd || bwd wavefront DP + in-block combine. ONE launch.
// wave 0: forward (alpha base-2, row-major -> aw; logZ2 -> LDS).
// wave 1: backward (g = beta base-2, row-major -> out).
// Theta is read DIRECTLY (row-major, scattered): rounds 8/9 proved the DP
// step time is insensitive to memory pattern, and loads are prefetched 8
// slots (~6000 cyc) ahead. The 1/ln2 pre-scale folds into an fmaf.
// After __syncthreads (drains both waves' stores; block-visible), both
// waves stream out = (alpha + g - logZ2) * ln2.
// ---------------------------------------------------------------------------

#define F2LOAD(P, dd) do {                                                     \
    const int dc_ = (dd) > 254 ? 254 : (dd);                                   \
    const int ca_ = clamp127(dc_ - jA), cb_ = clamp127(dc_ - jB);              \
    const float* pa_ = th + (ca_ * Mc + jA) * 3;                               \
    const float* pb_ = th + (cb_ * Mc + jB) * 3;                               \
    P##0 = pa_[0]; P##1 = pa_[1]; P##2 = pa_[2];                               \
    P##3 = pb_[0]; P##4 = pb_[1]; P##5 = pb_[2];                               \
  } while (0)

#define F2STEP(P, dd) do {                                                     \
    const int iA_ = (dd) - jA, iB_ = (dd) - jB;                                \
    const bool okA_ = (unsigned)iA_ < (unsigned)Nc;                            \
    const bool okB_ = (unsigned)iB_ < (unsigned)Nc;                            \
    const float g0 = mS2 + lg2(wS20 * E00 + wS21 * E10 + wS22 * E20);          \
    const float g1 = mPA + lg2(wPA0 * E01 + wPA1 * E11 + wPA2 * E21);          \
    const float g2 = mS1 + lg2(wS10 * E02 + wS11 * E12 + wS12 * E22);          \
    const float cA0 = okA_ ? fmaf(P##0, INVLN2, g0) : HNEG2;                   \
    const float cA1 = okA_ ? fmaf(P##1, INVLN2, g1) : HNEG2;                   \
    const float cA2 = okA_ ? fmaf(P##2, INVLN2, g2) : HNEG2;                   \
    st3_even(okA_ ? aw + (iA_ * Mc + jA) * 3 : dmpE, cA0, cA1, cA2);           \
    const float h0 = mPP + lg2(wPP0 * E00 + wPP1 * E10 + wPP2 * E20);          \
    const float h1 = mPB + lg2(wPB0 * E01 + wPB1 * E11 + wPB2 * E21);          \
    const float h2 = mPA + lg2(wPA0 * E02 + wPA1 * E12 + wPA2 * E22);          \
    const float cB0 = okB_ ? fmaf(P##3, INVLN2, h0) : HNEG2;                   \
    const float cB1 = okB_ ? fmaf(P##4, INVLN2, h1) : HNEG2;                   \
    const float cB2 = okB_ ? fmaf(P##5, INVLN2, h2) : HNEG2;                   \
    st3_odd(okB_ ? aw + (iB_ * Mc + jB) * 3 : dmpO, cB0, cB1, cB2);            \
    const float mA_ = fmaxf(fmaxf(cA0, cA1), cA2);                             \
    const float a0_ = ex2(cA0 - mA_), a1_ = ex2(cA1 - mA_),                    \
                a2_ = ex2(cA2 - mA_);                                          \
    const float mB_ = fmaxf(fmaxf(cB0, cB1), cB2);                             \
    const float b0_ = ex2(cB0 - mB_), b1_ = ex2(cB1 - mB_),                    \
                b2_ = ex2(cB2 - mB_);                                          \
    mPP = mPA; wPP0 = wPA0; wPP1 = wPA1; wPP2 = wPA2;                          \
    mPA = mA_; wPA0 = a0_; wPA1 = a1_; wPA2 = a2_;                             \
    mPB = mB_; wPB0 = b0_; wPB1 = b1_; wPB2 = b2_;                             \
    mS2 = mS1; wS20 = wS10; wS21 = wS11; wS22 = wS12;                          \
    mS1 = shr1f(mB_, HNEG2);                                                   \
    wS10 = shr1f(b0_, 1.f); wS11 = shr1f(b1_, 1.f); wS12 = shr1f(b2_, 1.f);    \
  } while (0)

#define B2LOADL(Pt, dd) do {                                                   \
    int dor_ = 254 - (dd); if (dor_ < 0) dor_ = 0;                             \
    const int ca_ = clamp127(dor_ - jjA), cb_ = clamp127(dor_ - jjB);          \
    const float* pa_ = th + (ca_ * Mc + jjA) * 3;                              \
    const float* pb_ = th + (cb_ * Mc + jjB) * 3;                              \
    Pt##0 = pa_[0]; Pt##1 = pa_[1]; Pt##2 = pa_[2];                            \
    Pt##3 = pb_[0]; Pt##4 = pb_[1]; Pt##5 = pb_[2];                            \
  } while (0)

#define B2STEPL(Pt, dd) do {                                                   \
    const int iA_ = Nc - 1 - (dd) + jA;                                        \
    const int iB_ = Nc - 1 - (dd) + jB;                                        \
    const bool okA_ = (unsigned)iA_ < (unsigned)Nc;                            \
    const bool okB_ = (unsigned)iB_ < (unsigned)Nc;                            \
    float uA0, uA1, uA2, uB0, uB1, uB2;                                        \
    {                                                                          \
      const float v0 = S2u0, v1 = pAu1, v2 = S1u2;                             \
      const float mv = fmaxf(fmaxf(v0, v1), v2);                               \
      const float w0 = ex2(v0 - mv), w1 = ex2(v1 - mv), w2 = ex2(v2 - mv);     \
      float g0 = mv + lg2(w0 * E00 + w1 * E01 + w2 * E02);                     \
      float g1 = mv + lg2(w0 * E10 + w1 * E11 + w2 * E12);                     \
      float g2 = mv + lg2(w0 * E20 + w1 * E21 + w2 * E22);                     \
      if ((dd) == 0 && l == 0) { g0 = 0.f; g1 = 0.f; g2 = 0.f; }               \
      uA0 = okA_ ? fmaf(Pt##0, INVLN2, g0) : HNEG2;                            \
      uA1 = okA_ ? fmaf(Pt##1, INVLN2, g1) : HNEG2;                            \
      uA2 = okA_ ? fmaf(Pt##2, INVLN2, g2) : HNEG2;                            \
      st3_odd(okA_ ? ob + (iA_ * Mc + jjA) * 3 : dmpO, g0, g1, g2);            \
    }                                                                          \
    {                                                                          \
      const float v0 = ppAu0, v1 = pBu1, v2 = pAu2;                            \
      const float mv = fmaxf(fmaxf(v0, v1), v2);                               \
      const float w0 = ex2(v0 - mv), w1 = ex2(v1 - mv), w2 = ex2(v2 - mv);     \
      const float g0 = mv + lg2(w0 * E00 + w1 * E01 + w2 * E02);               \
      const float g1 = mv + lg2(w0 * E10 + w1 * E11 + w2 * E12);               \
      const float g2 = mv + lg2(w0 * E20 + w1 * E21 + w2 * E22);               \
      uB0 = okB_ ? fmaf(Pt##3, INVLN2, g0) : HNEG2;                            \
      uB1 = okB_ ? fmaf(Pt##4, INVLN2, g1) : HNEG2;                            \
      uB2 = okB_ ? fmaf(Pt##5, INVLN2, g2) : HNEG2;                            \
      st3_even(okB_ ? ob + (iB_ * Mc + jjB) * 3 : dmpE, g0, g1, g2);           \
    }                                                                          \
    ppAu0 = pAu0; pAu0 = uA0; pAu1 = uA1; pAu2 = uA2; pBu1 = uB1;              \
    S2u0 = S1u0;                                                               \
    S1u0 = shr1f(uB0, HNEG2);                                                  \
    S1u2 = shr1f(uB2, HNEG2);                                                  \
  } while (0)

__global__ __launch_bounds__(128, 1) void fbf_kernel(
    const float* __restrict__ theta, const float* __restrict__ A,
    float* __restrict__ aw_, float* __restrict__ ob_) {
  const int b = blockIdx.x;
  const int wave = threadIdx.x >> 6;
  const int l = threadIdx.x & 63;
  const float* th = theta + (size_t)b * CELLS;
  const float* Ab = A + b * 9;
  // E = e^A: identical weights in the base-2 formulation (2^(A/ln2) = e^A).
  const float E00 = __expf(Ab[0]), E01 = __expf(Ab[1]), E02 = __expf(Ab[2]);
  const float E10 = __expf(Ab[3]), E11 = __expf(Ab[4]), E12 = __expf(Ab[5]);
  const float E20 = __expf(Ab[6]), E21 = __expf(Ab[7]), E22 = __expf(Ab[8]);

  __shared__ float sLZ;  // logZ2, wave0 -> combine phase

  const int jA = 2 * l, jB = 2 * l + 1;
  float* aw = aw_ + (size_t)b * AWSTRIDE;
  float* ob = ob_ + (size_t)b * CELLS;
  float* dpad = aw + CELLS;  // 16-float dump pad

  if (wave == 0) {
    // ----------------- forward (base-2) -----------------
    float* dmpE = dpad;      // even-column dump (8B aligned)
    float* dmpO = dpad + 3;  // odd-column dump

    float mPA = HNEG2, wPA0 = 1.f, wPA1 = 1.f, wPA2 = 1.f;
    float mPB = HNEG2, wPB0 = 1.f, wPB1 = 1.f, wPB2 = 1.f;
    float mPP = HNEG2, wPP0 = 1.f, wPP1 = 1.f, wPP2 = 1.f;
    float mS1 = HNEG2, wS10 = 1.f, wS11 = 1.f, wS12 = 1.f;
    float mS2 = HNEG2, wS20 = 1.f, wS21 = 1.f, wS22 = 1.f;
    // Origin (0,0): lane 0's first g0 must be 0: mS2=0, wS2·Ecol0 = 1.
    if (l == 0) { mS2 = 0.f; wS20 = 1.0f / E00; wS21 = 0.f; wS22 = 0.f; }

    DECL6(xt0); DECL6(xt1); DECL6(xt2); DECL6(xt3);
    DECL6(yt0); DECL6(yt1); DECL6(yt2); DECL6(yt3);

    F2LOAD(xt0, 0); F2LOAD(xt1, 1); F2LOAD(xt2, 2); F2LOAD(xt3, 3);
    F2LOAD(yt0, 4); F2LOAD(yt1, 5); F2LOAD(yt2, 6); F2LOAD(yt3, 7);

    for (int t = 0; t < 31; ++t) {
      const int d0 = 8 * t;
      F2STEP(xt0, d0 + 0); F2STEP(xt1, d0 + 1); F2STEP(xt2, d0 + 2); F2STEP(xt3, d0 + 3);
      F2LOAD(xt0, d0 + 8); F2LOAD(xt1, d0 + 9); F2LOAD(xt2, d0 + 10); F2LOAD(xt3, d0 + 11);
      F2STEP(yt0, d0 + 4); F2STEP(yt1, d0 + 5); F2STEP(yt2, d0 + 6); F2STEP(yt3, d0 + 7);
      F2LOAD(yt0, d0 + 12); F2LOAD(yt1, d0 + 13); F2LOAD(yt2, d0 + 14); F2LOAD(yt3, d0 + 15);
    }
    // Tail: diagonals 248..254.
    F2STEP(xt0, 248); F2STEP(xt1, 249); F2STEP(xt2, 250); F2STEP(xt3, 251);
    F2STEP(yt0, 252); F2STEP(yt1, 253); F2STEP(yt2, 254);
    // lane 63's B state holds cell (127,127): logZ2 = mPB + log2(Σ wPB).
    if (l == 63) sLZ = mPB + lg2(wPB0 + wPB1 + wPB2);
  } else {
    // ----------------- backward (beta only, base-2) -----------------
    const int jjA = Mc - 1 - jA, jjB = Mc - 1 - jB;  // orig cols
    float* dmpE = dpad + 8;   // even-column dump (8B aligned)
    float* dmpO = dpad + 11;  // odd-column dump

    float pAu0 = HNEG2, pAu1 = HNEG2, pAu2 = HNEG2;
    float ppAu0 = HNEG2, pBu1 = HNEG2;
    float S1u0 = HNEG2, S1u2 = HNEG2, S2u0 = HNEG2;

    DECL6(xt0); DECL6(xt1); DECL6(xt2); DECL6(xt3);
    DECL6(yt0); DECL6(yt1); DECL6(yt2); DECL6(yt3);

    B2LOADL(xt0, 0); B2LOADL(xt1, 1); B2LOADL(xt2, 2); B2LOADL(xt3, 3);
    B2LOADL(yt0, 4); B2LOADL(yt1, 5); B2LOADL(yt2, 6); B2LOADL(yt3, 7);

    for (int t = 0; t < 31; ++t) {
      const int d0 = 8 * t;
      B2STEPL(xt0, d0 + 0); B2STEPL(xt1, d0 + 1);
      B2STEPL(xt2, d0 + 2); B2STEPL(xt3, d0 + 3);
      B2LOADL(xt0, d0 + 8); B2LOADL(xt1, d0 + 9);
      B2LOADL(xt2, d0 + 10); B2LOADL(xt3, d0 + 11);
      B2STEPL(yt0, d0 + 4); B2STEPL(yt1, d0 + 5);
      B2STEPL(yt2, d0 + 6); B2STEPL(yt3, d0 + 7);
      B2LOADL(yt0, d0 + 12); B2LOADL(yt1, d0 + 13);
      B2LOADL(yt2, d0 + 14); B2LOADL(yt3, d0 + 15);
    }
    B2STEPL(xt0, 248); B2STEPL(xt1, 249); B2STEPL(xt2, 250); B2STEPL(xt3, 251);
    B2STEPL(yt0, 252); B2STEPL(yt1, 253); B2STEPL(yt2, 254);
  }

  // ---- combine: out = (alpha2 + g2 - logZ2) * ln2, float4 streaming ----
  // __syncthreads drains both waves' vmem stores; same-CU L1 makes them
  // visible to all 128 threads.
  __syncthreads();
  const float lz = sLZ;
  const float4* a4 = (const float4*)aw;
  float4* o4 = (float4*)ob;
#pragma unroll 4
  for (int k = threadIdx.x; k < CELLS / 4; k += 128) {
    const float4 a = a4[k];
    const float4 g = o4[k];
    o4[k] = make_float4((a.x + g.x - lz) * LN2F, (a.y + g.y - lz) * LN2F,
                        (a.z + g.z - lz) * LN2F, (a.w + g.w - lz) * LN2F);
  }
}

// ---------------------------------------------------------------------------
// Fallback (known-correct ~355 us): used only if ws small.
// ---------------------------------------------------------------------------
__global__ __launch_bounds__(128) void fwd_fb(const float* __restrict__ theta,
                                              const float* __restrict__ A,
                                              float* __restrict__ out) {
  const int b = blockIdx.x;
  const int j = threadIdx.x;
  const float* th = theta + (size_t)b * CELLS;
  float* ob = out + (size_t)b * CELLS;

  __shared__ float sA[9];
  __shared__ float ring[3][Mc + 1][3];
  if (j < 9) sA[j] = A[b * 9 + j];
  {
    float* rf = &ring[0][0][0];
    for (int t = j; t < 3 * (Mc + 1) * 3; t += Mc) rf[t] = HNEG;
  }
  __syncthreads();
  const float A00 = sA[0], A01 = sA[1], A02 = sA[2];
  const float A10 = sA[3], A11 = sA[4], A12 = sA[5];
  const float A20 = sA[6], A21 = sA[7], A22 = sA[8];

  float p0 = HNEG, p1 = HNEG, p2 = HNEG;
  float tc0 = 0.f, tc1 = 0.f, tc2 = 0.f, tn0 = 0.f, tn1 = 0.f, tn2 = 0.f;
  if (j == 0) { tc0 = th[0]; tc1 = th[1]; tc2 = th[2]; }
  if (j <= 1) {
    const int i1 = 1 - j;
    const float* p = th + (i1 * Mc + j) * 3;
    tn0 = p[0]; tn1 = p[1]; tn2 = p[2];
  }
  int s0 = 0, s1 = 2, s2 = 1;
  for (int d = 0; d < Nc + Mc - 1; ++d) {
    const int i = d - j;
    float tf0 = 0.f, tf1 = 0.f, tf2 = 0.f;
    const int ip = i + 2;
    if (ip >= 0 && ip < Nc) {
      const float* p = th + (ip * Mc + j) * 3;
      tf0 = p[0]; tf1 = p[1]; tf2 = p[2];
    }
    float c0 = HNEG, c1 = HNEG, c2 = HNEG;
    if (i >= 0 && i < Nc) {
      const float* nd1 = ring[s1][j];
      const float* nd2 = ring[s2][j];
      float lm = lse3(nd2[0] + A00, nd2[1] + A10, nd2[2] + A20);
      if (i == 0 && j == 0) lm = 0.0f;
      float lx = lse3(p0 + A01, p1 + A11, p2 + A21);
      float ly = lse3(nd1[0] + A02, nd1[1] + A12, nd1[2] + A22);
      c0 = tc0 + lm; c1 = tc1 + lx; c2 = tc2 + ly;
      float* o = ob + (i * Mc + j) * 3;
      o[0] = c0; o[1] = c1; o[2] = c2;
    }
    float* w = ring[s0][j + 1];
    w[0] = c0; w[1] = c1; w[2] = c2;
    __syncthreads();
    p0 = c0; p1 = c1; p2 = c2;
    tc0 = tn0; tc1 = tn1; tc2 = tn2;
    tn0 = tf0; tn1 = tf1; tn2 = tf2;
    const int t = s2; s2 = s1; s1 = s0; s0 = t;
  }
}

__global__ __launch_bounds__(128) void bwd_fb(const float* __restrict__ theta,
                                              const float* __restrict__ A,
                                              float* __restrict__ ob_) {
  const int b = blockIdx.x;
  const int q = threadIdx.x;
  const float* th = theta + (size_t)b * CELLS;
  float* ob = ob_ + (size_t)b * CELLS;

  __shared__ float sA[9];
  __shared__ float ring[3][Mc + 1][3];
  __shared__ float sZ;
  if (q < 9) sA[q] = A[b * 9 + q];
  {
    float* rf = &ring[0][0][0];
    for (int t = q; t < 3 * (Mc + 1) * 3; t += Mc) rf[t] = HNEG;
  }
  if (q == 0) {
    sZ = lse3(ob[(Nc * Mc - 1) * 3 + 0], ob[(Nc * Mc - 1) * 3 + 1],
              ob[(Nc * Mc - 1) * 3 + 2]);
  }
  __syncthreads();
  const float A00 = sA[0], A01 = sA[1], A02 = sA[2];
  const float A10 = sA[3], A11 = sA[4], A12 = sA[5];
  const float A20 = sA[6], A21 = sA[7], A22 = sA[8];
  const float logZ = sZ;

  const int jj = Mc - 1 - q;
  float pu1 = HNEG;
  float tc0 = 0.f, tc1 = 0.f, tc2 = 0.f, tn0 = 0.f, tn1 = 0.f, tn2 = 0.f;
  float ac0 = 0.f, ac1 = 0.f, ac2 = 0.f, an0 = 0.f, an1 = 0.f, an2 = 0.f;
  if (q == 0) {
    const float* p = th + ((Nc - 1) * Mc + jj) * 3;
    tc0 = p[0]; tc1 = p[1]; tc2 = p[2];
    const float* a = ob + ((Nc - 1) * Mc + jj) * 3;
    ac0 = a[0]; ac1 = a[1]; ac2 = a[2];
  }
  if (q <= 1) {
    const int i1 = Nc - 2 + q;
    const float* p = th + (i1 * Mc + jj) * 3;
    tn0 = p[0]; tn1 = p[1]; tn2 = p[2];
    const float* a = ob + (i1 * Mc + jj) * 3;
    an0 = a[0]; an1 = a[1]; an2 = a[2];
  }
  int s0 = 0, s1 = 2, s2 = 1;
  for (int d = 0; d < Nc + Mc - 1; ++d) {
    const int p = d - q;
    const int i = Nc - 1 - p;
    float tf0 = 0.f, tf1 = 0.f, tf2 = 0.f, af0 = 0.f, af1 = 0.f, af2 = 0.f;
    const int ipf = i - 2;
    if (ipf >= 0 && ipf < Nc) {
      const float* pp = th + (ipf * Mc + jj) * 3;
      tf0 = pp[0]; tf1 = pp[1]; tf2 = pp[2];
      const float* aa = ob + (ipf * Mc + jj) * 3;
      af0 = aa[0]; af1 = aa[1]; af2 = aa[2];
    }
    float u0 = HNEG, u1 = HNEG, u2 = HNEG;
    if (p >= 0 && p < Nc) {
      const float* nd1 = ring[s1][q];
      const float* nd2 = ring[s2][q];
      const float v0 = nd2[0];
      const float v1 = pu1;
      const float v2 = nd1[2];
      float g0 = lse3(A00 + v0, A01 + v1, A02 + v2);
      float g1 = lse3(A10 + v0, A11 + v1, A12 + v2);
      float g2 = lse3(A20 + v0, A21 + v1, A22 + v2);
      if (p == 0 && q == 0) { g0 = 0.0f; g1 = 0.0f; g2 = 0.0f; }
      u0 = g0 + tc0; u1 = g1 + tc1; u2 = g2 + tc2;
      float* o = ob + (i * Mc + jj) * 3;
      o[0] = ac0 + g0 - logZ;
      o[1] = ac1 + g1 - logZ;
      o[2] = ac2 + g2 - logZ;
    }
    float* w = ring[s0][q + 1];
    w[0] = u0; w[1] = u1; w[2] = u2;
    __syncthreads();
    pu1 = u1;
    tc0 = tn0; tc1 = tn1; tc2 = tn2;
    tn0 = tf0; tn1 = tf1; tn2 = tf2;
    ac0 = an0; ac1 = an1; ac2 = an2;
    an0 = af0; an1 = af1; an2 = af2;
    const int t = s2; s2 = s1; s1 = s0; s0 = t;
  }
}

extern "C" void kernel_launch(void* const* d_in, const int* in_sizes, int n_in,
                              void* d_out, int out_size, void* d_ws, size_t ws_size,
                              hipStream_t stream) {
  const float* theta = (const float*)d_in[0];
  const float* A = (const float*)d_in[1];
  float* out = (float*)d_out;
  const int B = in_sizes[1] / 9;  // A is (B, 3, 3)

  // Only workspace: alpha (row-major, base-2) + dump pad per batch.
  const size_t need = (size_t)B * AWSTRIDE * 4;
  if (ws_size >= need) {
    float* aw = (float*)d_ws;
    fbf_kernel<<<dim3(B), dim3(128), 0, stream>>>(theta, A, aw, out);
  } else {
    fwd_fb<<<dim3(B), dim3(128), 0, stream>>>(theta, A, out);
    bwd_fb<<<dim3(B), dim3(128), 0, stream>>>(theta, A, out);
  }
}